// Round 1
// baseline (1690.393 us; speedup 1.0000x reference)
//
#include <hip/hip_runtime.h>
#include <hip/hip_bf16.h>
#include <math.h>

// Problem constants (fixed by the reference)
#define NN       10000      // nodes
#define F_IN     128
#define HID      300
#define H1       5
#define H3       3
#define NCLS     40
#define HC1      (H1*HID)   // 1500
#define HC3      (H3*NCLS)  // 120
#define NEG_SLOPE 0.2f
#define EPSV     1e-16f

// ---------------------------------------------------------------------------
// CSR build
// ---------------------------------------------------------------------------
__global__ void k_count(const int* __restrict__ ei, int* __restrict__ counts,
                        int E0, int Etot) {
  int e = blockIdx.x * 256 + threadIdx.x;
  if (e >= Etot) return;
  int dst = (e < E0) ? ei[E0 + e] : (e - E0);
  atomicAdd(&counts[dst], 1);
}

__global__ __launch_bounds__(256) void k_scan(const int* __restrict__ counts,
                                              int* __restrict__ offsets,
                                              int* __restrict__ cursor,
                                              int N, int Etot) {
  __shared__ int sh[256];
  const int CH = 40;  // 256*40 = 10240 >= N
  int t = threadIdx.x;
  int base = t * CH;
  int s = 0;
  for (int i = 0; i < CH; i++) {
    int idx = base + i;
    if (idx < N) s += counts[idx];
  }
  sh[t] = s;
  __syncthreads();
  for (int d = 1; d < 256; d <<= 1) {
    int v = (t >= d) ? sh[t - d] : 0;
    __syncthreads();
    sh[t] += v;
    __syncthreads();
  }
  int run = sh[t] - s;  // exclusive prefix
  for (int i = 0; i < CH; i++) {
    int idx = base + i;
    if (idx < N) {
      offsets[idx] = run;
      cursor[idx] = run;
      run += counts[idx];
    }
  }
  if (t == 0) offsets[N] = Etot;
}

__global__ void k_scatter(const int* __restrict__ ei, int* __restrict__ cursor,
                          int* __restrict__ csr_src, int E0, int Etot) {
  int e = blockIdx.x * 256 + threadIdx.x;
  if (e >= Etot) return;
  int src, dst;
  if (e < E0) { src = ei[e]; dst = ei[E0 + e]; }
  else        { src = dst = e - E0; }
  int pos = atomicAdd(&cursor[dst], 1);
  csr_src[pos] = src;
}

// ---------------------------------------------------------------------------
// GEMM: C[M,N] = A[M,K] @ B[K,N], fp32, 64x64 tile, BK=16, 256 thr, 4x4/thr
// ---------------------------------------------------------------------------
__global__ __launch_bounds__(256) void gemm_f32(const float* __restrict__ A,
                                                const float* __restrict__ B,
                                                float* __restrict__ C,
                                                int M, int K, int N) {
  __shared__ float As[16][68];  // +4 pad: kills 16-way store conflict, keeps 16B align
  __shared__ float Bs[16][64];
  int tid = threadIdx.x;
  int bm = blockIdx.y * 64, bn = blockIdx.x * 64;
  int tx = tid & 15, ty = tid >> 4;
  int a_c = tid & 15, a_r = tid >> 4;   // A: k-col, m-row base
  int b_c = tid & 63, b_r = tid >> 6;   // B: n-col, k-row base
  float acc[4][4] = {};
  for (int kt = 0; kt < K; kt += 16) {
#pragma unroll
    for (int p = 0; p < 4; p++) {
      int r = a_r + p * 16;
      int gm = bm + r, gk = kt + a_c;
      As[a_c][r] = (gm < M && gk < K) ? A[(size_t)gm * K + gk] : 0.f;
    }
#pragma unroll
    for (int p = 0; p < 4; p++) {
      int r = b_r + p * 4;
      int gk = kt + r, gn = bn + b_c;
      Bs[r][b_c] = (gk < K && gn < N) ? B[(size_t)gk * N + gn] : 0.f;
    }
    __syncthreads();
#pragma unroll
    for (int k = 0; k < 16; k++) {
      float a[4], b[4];
#pragma unroll
      for (int i = 0; i < 4; i++) a[i] = As[k][ty * 4 + i];
#pragma unroll
      for (int j = 0; j < 4; j++) b[j] = Bs[k][tx * 4 + j];
#pragma unroll
      for (int i = 0; i < 4; i++)
#pragma unroll
        for (int j = 0; j < 4; j++) acc[i][j] += a[i] * b[j];
    }
    __syncthreads();
  }
#pragma unroll
  for (int i = 0; i < 4; i++) {
    int gm = bm + ty * 4 + i;
    if (gm >= M) continue;
#pragma unroll
    for (int j = 0; j < 4; j++) {
      int gn = bn + tx * 4 + j;
      if (gn < N) C[(size_t)gm * N + gn] = acc[i][j];
    }
  }
}

// ---------------------------------------------------------------------------
// Attention coefficients: asrc[n,h] = <h[n,h,:], att_src[h,:]>, same for dst
// One 64-thread block per node.
// ---------------------------------------------------------------------------
__global__ __launch_bounds__(64) void k_att(const float* __restrict__ hfeat,
                                            const float* __restrict__ att_s,
                                            const float* __restrict__ att_d,
                                            float* __restrict__ asrc,
                                            float* __restrict__ adst,
                                            int H, int C) {
  int n = blockIdx.x;
  int t = threadIdx.x;
  int HCv = H * C;
  const float* hr = hfeat + (size_t)n * HCv;
  for (int h = 0; h < H; h++) {
    float ps = 0.f, pd = 0.f;
    for (int c = t; c < C; c += 64) {
      float v = hr[h * C + c];
      ps += v * att_s[h * C + c];
      pd += v * att_d[h * C + c];
    }
    for (int o = 32; o > 0; o >>= 1) {
      ps += __shfl_down(ps, o);
      pd += __shfl_down(pd, o);
    }
    if (t == 0) {
      asrc[n * H + h] = ps;
      adst[n * H + h] = pd;
    }
  }
}

// ---------------------------------------------------------------------------
// Per-(node,head) softmax over incoming edges; writes normalized alpha.
// ---------------------------------------------------------------------------
__global__ void k_stats(const float* __restrict__ asrc,
                        const float* __restrict__ adst,
                        const int* __restrict__ csr_src,
                        const int* __restrict__ offsets,
                        float* __restrict__ alpha, int N, int H) {
  int t = blockIdx.x * 256 + threadIdx.x;
  if (t >= N * H) return;
  int n = t / H, h = t - n * H;
  int s0 = offsets[n], s1 = offsets[n + 1];
  float ad = adst[t];
  float m = -1e30f;
  for (int p = s0; p < s1; p++) {
    float v = asrc[csr_src[p] * H + h] + ad;
    v = v > 0.f ? v : NEG_SLOPE * v;
    m = fmaxf(m, v);
  }
  float sum = 0.f;
  for (int p = s0; p < s1; p++) {
    float v = asrc[csr_src[p] * H + h] + ad;
    v = v > 0.f ? v : NEG_SLOPE * v;
    float ex = expf(v - m);
    alpha[p * H + h] = ex;
    sum += ex;
  }
  float r = 1.f / (sum + EPSV);
  for (int p = s0; p < s1; p++) alpha[p * H + h] *= r;
}

// ---------------------------------------------------------------------------
// Aggregation: out[n,:] = sum_e alpha[e,h] * hfeat[src_e, :] (+epilogue)
// mode 0: +bias, elu   mode 1: +bias +prev, elu   mode 2: raw store
// One 256-thread block per node.
// ---------------------------------------------------------------------------
__global__ __launch_bounds__(256) void k_agg(const float* __restrict__ hfeat,
                                             const float* __restrict__ alpha,
                                             const int* __restrict__ csr_src,
                                             const int* __restrict__ offsets,
                                             const float* __restrict__ bias,
                                             const float* __restrict__ prev,
                                             float* __restrict__ out,
                                             int HCv, int C, int H, int mode) {
  int n = blockIdx.x;
  int t = threadIdx.x;
  int s0 = offsets[n], s1 = offsets[n + 1];
  float acc[6] = {0.f, 0.f, 0.f, 0.f, 0.f, 0.f};
  int cols[6], hidx[6];
  int nj = 0;
  for (int col = t; col < HCv; col += 256) {
    cols[nj] = col;
    hidx[nj] = col / C;
    nj++;
  }
  __shared__ int s_src[64];
  __shared__ float s_alpha[64 * 8];
  for (int base = s0; base < s1; base += 64) {
    int chunk = min(64, s1 - base);
    if (t < chunk) s_src[t] = csr_src[base + t];
    for (int i = t; i < chunk * H; i += 256) s_alpha[i] = alpha[base * H + i];
    __syncthreads();
    for (int e = 0; e < chunk; e++) {
      const float* hr = hfeat + (size_t)s_src[e] * HCv;
#pragma unroll
      for (int j = 0; j < 6; j++) {
        if (j < nj) acc[j] += s_alpha[e * H + hidx[j]] * hr[cols[j]];
      }
    }
    __syncthreads();
  }
  for (int j = 0; j < nj; j++) {
    int col = cols[j];
    float v = acc[j];
    if (mode <= 1) v += bias[col];
    if (mode == 1) v += prev[(size_t)n * HCv + col];
    if (mode <= 1) v = v > 0.f ? v : (expf(v) - 1.f);  // ELU
    out[(size_t)n * HCv + col] = v;
  }
}

// Layer-3 head mean + bias: h3[n,c] = mean_h agg[n,h,c] + b3[c]
__global__ void k_mean3(const float* __restrict__ agg, const float* __restrict__ b3,
                        float* __restrict__ h3, int N) {
  int t = blockIdx.x * 256 + threadIdx.x;
  if (t >= N * NCLS) return;
  int n = t / NCLS, c = t - n * NCLS;
  const float* a = agg + (size_t)n * HC3;
  h3[t] = (a[c] + a[NCLS + c] + a[2 * NCLS + c]) * (1.f / 3.f) + b3[c];
}

// Pooled column sums
__global__ void k_pool(const float* __restrict__ h3, float* __restrict__ pooled,
                       int N) {
  int col = threadIdx.x;  // blockDim = (64,4)
  if (col >= NCLS) return;
  int row = blockIdx.x * 4 + threadIdx.y;
  int stride = gridDim.x * 4;
  float acc = 0.f;
  for (int r = row; r < N; r += stride) acc += h3[(size_t)r * NCLS + col];
  atomicAdd(&pooled[col], acc);
}

// pooled -> out[0:40], log_softmax(pooled) -> out[40:80]
__global__ __launch_bounds__(64) void k_final(const float* __restrict__ pooled,
                                              float* __restrict__ out) {
  int t = threadIdx.x;
  float v = (t < NCLS) ? pooled[t] : -INFINITY;
  float m = v;
  for (int o = 32; o > 0; o >>= 1) m = fmaxf(m, __shfl_xor(m, o));
  float ex = (t < NCLS) ? expf(v - m) : 0.f;
  float s = ex;
  for (int o = 32; o > 0; o >>= 1) s += __shfl_xor(s, o);
  float lse = m + logf(s);
  if (t < NCLS) {
    out[t] = v;
    out[NCLS + t] = v - lse;
  }
}

// ---------------------------------------------------------------------------
extern "C" void kernel_launch(void* const* d_in, const int* in_sizes, int n_in,
                              void* d_out, int out_size, void* d_ws, size_t ws_size,
                              hipStream_t stream) {
  const float* x   = (const float*)d_in[0];
  const int*   ei  = (const int*)d_in[1];
  const float* W1  = (const float*)d_in[2];
  const float* as1 = (const float*)d_in[3];
  const float* ad1 = (const float*)d_in[4];
  const float* b1  = (const float*)d_in[5];
  const float* W2  = (const float*)d_in[6];
  const float* as2 = (const float*)d_in[7];
  const float* ad2 = (const float*)d_in[8];
  const float* b2  = (const float*)d_in[9];
  const float* W3  = (const float*)d_in[10];
  const float* as3 = (const float*)d_in[11];
  const float* ad3 = (const float*)d_in[12];
  const float* b3  = (const float*)d_in[13];
  float* out = (float*)d_out;

  const int N = NN;
  const int E0 = in_sizes[1] / 2;   // 80000
  const int Etot = E0 + N;          // 90000

  // workspace layout (floats)
  const size_t NF = (size_t)N * HC1;  // 15M
  float* f = (float*)d_ws;
  float* hfeat  = f;            // [N,1500] GEMM output (reused all layers)
  float* hbuf1  = f + NF;       // layer1 output h (post-ELU); later: layer3 agg + h3
  float* hbuf2  = f + 2 * NF;   // layer2 combined output
  float* asrc   = f + 3 * NF;                       // [N,5]
  float* adst   = asrc + (size_t)N * H1;            // [N,5]
  float* alphab = adst + (size_t)N * H1;            // [Etot,5]
  float* pooled = alphab + (size_t)Etot * H1;       // [64]
  int* ibase   = (int*)(pooled + 64);
  int* counts  = ibase;
  int* offsets = counts + N;        // N+1
  int* cursor  = offsets + N + 1;
  int* csr_src = cursor + N;        // Etot
  float* aggout = hbuf1;            // [N,120] layer3 aggregation (hbuf1 free then)
  float* h3     = hbuf1 + 2000000;  // [N,40], disjoint from aggout

  hipMemsetAsync(counts, 0, (size_t)N * sizeof(int), stream);
  hipMemsetAsync(pooled, 0, 64 * sizeof(float), stream);

  // CSR build
  k_count<<<(Etot + 255) / 256, 256, 0, stream>>>(ei, counts, E0, Etot);
  k_scan<<<1, 256, 0, stream>>>(counts, offsets, cursor, N, Etot);
  k_scatter<<<(Etot + 255) / 256, 256, 0, stream>>>(ei, cursor, csr_src, E0, Etot);

  // ---- Layer 1: GATConv(x; W1) -> hbuf1, concat, +b1, ELU
  {
    dim3 grid((HC1 + 63) / 64, (N + 63) / 64);
    gemm_f32<<<grid, 256, 0, stream>>>(x, W1, hfeat, N, F_IN, HC1);
    k_att<<<N, 64, 0, stream>>>(hfeat, as1, ad1, asrc, adst, H1, HID);
    k_stats<<<(N * H1 + 255) / 256, 256, 0, stream>>>(asrc, adst, csr_src, offsets,
                                                      alphab, N, H1);
    k_agg<<<N, 256, 0, stream>>>(hfeat, alphab, csr_src, offsets, b1, nullptr,
                                 hbuf1, HC1, HID, H1, 0);
  }

  // ---- Layer 2: GATConv(hbuf1; W2), h = elu(hbuf1 + conv2) -> hbuf2
  {
    dim3 grid((HC1 + 63) / 64, (N + 63) / 64);
    gemm_f32<<<grid, 256, 0, stream>>>(hbuf1, W2, hfeat, N, HC1, HC1);
    k_att<<<N, 64, 0, stream>>>(hfeat, as2, ad2, asrc, adst, H1, HID);
    k_stats<<<(N * H1 + 255) / 256, 256, 0, stream>>>(asrc, adst, csr_src, offsets,
                                                      alphab, N, H1);
    k_agg<<<N, 256, 0, stream>>>(hfeat, alphab, csr_src, offsets, b2, hbuf1,
                                 hbuf2, HC1, HID, H1, 1);
  }

  // ---- Layer 3: GATConv(hbuf2; W3), mean over heads, +b3 -> h3
  {
    dim3 grid((HC3 + 63) / 64, (N + 63) / 64);
    gemm_f32<<<grid, 256, 0, stream>>>(hbuf2, W3, hfeat, N, HC1, HC3);
    k_att<<<N, 64, 0, stream>>>(hfeat, as3, ad3, asrc, adst, H3, NCLS);
    k_stats<<<(N * H3 + 255) / 256, 256, 0, stream>>>(asrc, adst, csr_src, offsets,
                                                      alphab, N, H3);
    k_agg<<<N, 256, 0, stream>>>(hfeat, alphab, csr_src, offsets, nullptr, nullptr,
                                 aggout, HC3, NCLS, H3, 2);
    k_mean3<<<(N * NCLS + 255) / 256, 256, 0, stream>>>(aggout, b3, h3, N);
  }

  // ---- Pool + log_softmax
  k_pool<<<64, dim3(64, 4), 0, stream>>>(h3, pooled, N);
  k_final<<<1, 64, 0, stream>>>(pooled, out);
}

// Round 2
// 833.662 us; speedup vs baseline: 2.0277x; 2.0277x over previous
//
#include <hip/hip_runtime.h>
#include <hip/hip_bf16.h>
#include <math.h>

// Problem constants (fixed by the reference)
#define NN       10000      // nodes
#define F_IN     128
#define HID      300
#define H1       5
#define H3       3
#define NCLS     40
#define HC1      (H1*HID)   // 1500
#define HC3      (H3*NCLS)  // 120
#define KPAD     1504       // 1500 padded to multiple of 32
#define NEG_SLOPE 0.2f
#define EPSV     1e-16f

typedef __attribute__((ext_vector_type(8))) short bf16x8;
typedef __attribute__((ext_vector_type(4))) float f32x4;

__device__ inline unsigned short f2bf(float f) {
  unsigned int u = __builtin_bit_cast(unsigned int, f);
  unsigned int r = (u + 0x7FFFu + ((u >> 16) & 1u)) >> 16;   // RNE
  return (unsigned short)r;
}

// ---------------------------------------------------------------------------
// CSR build
// ---------------------------------------------------------------------------
__global__ void k_count(const int* __restrict__ ei, int* __restrict__ counts,
                        int E0, int Etot) {
  int e = blockIdx.x * 256 + threadIdx.x;
  if (e >= Etot) return;
  int dst = (e < E0) ? ei[E0 + e] : (e - E0);
  atomicAdd(&counts[dst], 1);
}

__global__ __launch_bounds__(256) void k_scan(const int* __restrict__ counts,
                                              int* __restrict__ offsets,
                                              int* __restrict__ cursor,
                                              int N, int Etot) {
  __shared__ int sh[256];
  const int CH = 40;  // 256*40 = 10240 >= N
  int t = threadIdx.x;
  int base = t * CH;
  int s = 0;
  for (int i = 0; i < CH; i++) {
    int idx = base + i;
    if (idx < N) s += counts[idx];
  }
  sh[t] = s;
  __syncthreads();
  for (int d = 1; d < 256; d <<= 1) {
    int v = (t >= d) ? sh[t - d] : 0;
    __syncthreads();
    sh[t] += v;
    __syncthreads();
  }
  int run = sh[t] - s;  // exclusive prefix
  for (int i = 0; i < CH; i++) {
    int idx = base + i;
    if (idx < N) {
      offsets[idx] = run;
      cursor[idx] = run;
      run += counts[idx];
    }
  }
  if (t == 0) offsets[N] = Etot;
}

__global__ void k_scatter(const int* __restrict__ ei, int* __restrict__ cursor,
                          int* __restrict__ csr_src, int E0, int Etot) {
  int e = blockIdx.x * 256 + threadIdx.x;
  if (e >= Etot) return;
  int src, dst;
  if (e < E0) { src = ei[e]; dst = ei[E0 + e]; }
  else        { src = dst = e - E0; }
  int pos = atomicAdd(&cursor[dst], 1);
  csr_src[pos] = src;
}

// ---------------------------------------------------------------------------
// fp32 -> bf16 casts (with zero K-padding, rewritten every call)
// ---------------------------------------------------------------------------
__global__ void k_cvt(const float* __restrict__ in, unsigned short* __restrict__ out,
                      int R, int C, int Cpad) {
  long long idx = (long long)blockIdx.x * 256 + threadIdx.x;
  if (idx >= (long long)R * Cpad) return;
  int r = (int)(idx / Cpad), c = (int)(idx - (long long)r * Cpad);
  out[idx] = (c < C) ? f2bf(in[(size_t)r * C + c]) : 0;
}

// in: [K][Nmat] row-major -> out: [Nmat][Kpad] (transposed, zero-padded)
__global__ void k_cvtT(const float* __restrict__ in, unsigned short* __restrict__ out,
                       int K, int Nmat, int Kpad) {
  long long idx = (long long)blockIdx.x * 256 + threadIdx.x;
  if (idx >= (long long)Nmat * Kpad) return;
  int n = (int)(idx / Kpad), k = (int)(idx - (long long)n * Kpad);
  out[idx] = (k < K) ? f2bf(in[(size_t)k * Nmat + n]) : 0;
}

// ---------------------------------------------------------------------------
// MFMA GEMM: C[M,Nmat] = A[M,Kpad](bf16) @ Bt[Nmat,Kpad](bf16)^T, fp32 out.
// 128x128 tile, BK=32, 256 thr = 4 waves (2x2), each wave 4x4 of 16x16x32.
// LDS rows padded to 40 bf16 (80B) -> uniform bank-group distribution.
// ---------------------------------------------------------------------------
#define BM 128
#define BN 128
#define BK 32
#define LDST 40   // BK + 8 pad (elements)

__global__ __launch_bounds__(256) void gemm_mfma(
    const unsigned short* __restrict__ A,   // [M][Kpad]
    const unsigned short* __restrict__ Bt,  // [Nmat][Kpad]
    float* __restrict__ C, int M, int Kpad, int Nmat) {
  __shared__ unsigned short As[BM * LDST];
  __shared__ unsigned short Bs[BN * LDST];
  int tid = threadIdx.x;
  int lane = tid & 63, wid = tid >> 6;
  int wm = wid >> 1, wn = wid & 1;
  int bm = blockIdx.y * BM, bn = blockIdx.x * BN;
  int quad = lane >> 4, l16 = lane & 15;

  f32x4 acc[4][4] = {};

  for (int kt = 0; kt < Kpad; kt += BK) {
#pragma unroll
    for (int h = 0; h < 2; h++) {
      int i = tid + h * 256;          // chunk id in [0,512)
      int row = i >> 2, seg = i & 3;  // 4x16B chunks per 64B row-slice
      int ar = bm + row; ar = ar < M ? ar : M - 1;
      float4 av = *(const float4*)(A + (size_t)ar * Kpad + kt + seg * 8);
      *(float4*)(As + row * LDST + seg * 8) = av;
      int br = bn + row; br = br < Nmat ? br : Nmat - 1;
      float4 bv = *(const float4*)(Bt + (size_t)br * Kpad + kt + seg * 8);
      *(float4*)(Bs + row * LDST + seg * 8) = bv;
    }
    __syncthreads();
    bf16x8 af[4], bfr[4];
#pragma unroll
    for (int i = 0; i < 4; i++) {
      af[i]  = *(const bf16x8*)(As + (wm * 64 + i * 16 + l16) * LDST + quad * 8);
      bfr[i] = *(const bf16x8*)(Bs + (wn * 64 + i * 16 + l16) * LDST + quad * 8);
    }
#pragma unroll
    for (int i = 0; i < 4; i++)
#pragma unroll
      for (int j = 0; j < 4; j++)
        acc[i][j] = __builtin_amdgcn_mfma_f32_16x16x32_bf16(af[i], bfr[j], acc[i][j], 0, 0, 0);
    __syncthreads();
  }

#pragma unroll
  for (int i = 0; i < 4; i++) {
    int rowb = bm + wm * 64 + i * 16 + quad * 4;
#pragma unroll
    for (int j = 0; j < 4; j++) {
      int col = bn + wn * 64 + j * 16 + l16;
      if (col < Nmat) {
#pragma unroll
        for (int r = 0; r < 4; r++) {
          int row = rowb + r;
          if (row < M) C[(size_t)row * Nmat + col] = acc[i][j][r];
        }
      }
    }
  }
}

// ---------------------------------------------------------------------------
// Attention coefficients: asrc[n,h] = <h[n,h,:], att_src[h,:]>, same for dst
// ---------------------------------------------------------------------------
__global__ __launch_bounds__(64) void k_att(const float* __restrict__ hfeat,
                                            const float* __restrict__ att_s,
                                            const float* __restrict__ att_d,
                                            float* __restrict__ asrc,
                                            float* __restrict__ adst,
                                            int H, int C) {
  int n = blockIdx.x;
  int t = threadIdx.x;
  int HCv = H * C;
  const float* hr = hfeat + (size_t)n * HCv;
  for (int h = 0; h < H; h++) {
    float ps = 0.f, pd = 0.f;
    for (int c = t; c < C; c += 64) {
      float v = hr[h * C + c];
      ps += v * att_s[h * C + c];
      pd += v * att_d[h * C + c];
    }
    for (int o = 32; o > 0; o >>= 1) {
      ps += __shfl_down(ps, o);
      pd += __shfl_down(pd, o);
    }
    if (t == 0) {
      asrc[n * H + h] = ps;
      adst[n * H + h] = pd;
    }
  }
}

// ---------------------------------------------------------------------------
// Per-(node,head) softmax over incoming edges; writes normalized alpha.
// ---------------------------------------------------------------------------
__global__ void k_stats(const float* __restrict__ asrc,
                        const float* __restrict__ adst,
                        const int* __restrict__ csr_src,
                        const int* __restrict__ offsets,
                        float* __restrict__ alpha, int N, int H) {
  int t = blockIdx.x * 256 + threadIdx.x;
  if (t >= N * H) return;
  int n = t / H, h = t - n * H;
  int s0 = offsets[n], s1 = offsets[n + 1];
  float ad = adst[t];
  float m = -1e30f;
  for (int p = s0; p < s1; p++) {
    float v = asrc[csr_src[p] * H + h] + ad;
    v = v > 0.f ? v : NEG_SLOPE * v;
    m = fmaxf(m, v);
  }
  float sum = 0.f;
  for (int p = s0; p < s1; p++) {
    float v = asrc[csr_src[p] * H + h] + ad;
    v = v > 0.f ? v : NEG_SLOPE * v;
    float ex = expf(v - m);
    alpha[p * H + h] = ex;
    sum += ex;
  }
  float r = 1.f / (sum + EPSV);
  for (int p = s0; p < s1; p++) alpha[p * H + h] *= r;
}

// ---------------------------------------------------------------------------
// Aggregation: out[n,:] = sum_e alpha[e,h] * hfeat[src_e, :] (+epilogue)
// mode 0: +bias, elu   mode 1: +bias +prev, elu   mode 2: raw store
// ---------------------------------------------------------------------------
__global__ __launch_bounds__(256) void k_agg(const float* __restrict__ hfeat,
                                             const float* __restrict__ alpha,
                                             const int* __restrict__ csr_src,
                                             const int* __restrict__ offsets,
                                             const float* __restrict__ bias,
                                             const float* __restrict__ prev,
                                             float* __restrict__ out,
                                             int HCv, int C, int H, int mode) {
  int n = blockIdx.x;
  int t = threadIdx.x;
  int s0 = offsets[n], s1 = offsets[n + 1];
  float acc[6] = {0.f, 0.f, 0.f, 0.f, 0.f, 0.f};
  int cols[6], hidx[6];
  int nj = 0;
  for (int col = t; col < HCv; col += 256) {
    cols[nj] = col;
    hidx[nj] = col / C;
    nj++;
  }
  __shared__ int s_src[64];
  __shared__ float s_alpha[64 * 8];
  for (int base = s0; base < s1; base += 64) {
    int chunk = min(64, s1 - base);
    if (t < chunk) s_src[t] = csr_src[base + t];
    for (int i = t; i < chunk * H; i += 256) s_alpha[i] = alpha[base * H + i];
    __syncthreads();
    for (int e = 0; e < chunk; e++) {
      const float* hr = hfeat + (size_t)s_src[e] * HCv;
#pragma unroll
      for (int j = 0; j < 6; j++) {
        if (j < nj) acc[j] += s_alpha[e * H + hidx[j]] * hr[cols[j]];
      }
    }
    __syncthreads();
  }
  for (int j = 0; j < nj; j++) {
    int col = cols[j];
    float v = acc[j];
    if (mode <= 1) v += bias[col];
    if (mode == 1) v += prev[(size_t)n * HCv + col];
    if (mode <= 1) v = v > 0.f ? v : (expf(v) - 1.f);  // ELU
    out[(size_t)n * HCv + col] = v;
  }
}

// Layer-3 head mean + bias: h3[n,c] = mean_h agg[n,h,c] + b3[c]
__global__ void k_mean3(const float* __restrict__ agg, const float* __restrict__ b3,
                        float* __restrict__ h3, int N) {
  int t = blockIdx.x * 256 + threadIdx.x;
  if (t >= N * NCLS) return;
  int n = t / NCLS, c = t - n * NCLS;
  const float* a = agg + (size_t)n * HC3;
  h3[t] = (a[c] + a[NCLS + c] + a[2 * NCLS + c]) * (1.f / 3.f) + b3[c];
}

// Pooled column sums
__global__ void k_pool(const float* __restrict__ h3, float* __restrict__ pooled,
                       int N) {
  int col = threadIdx.x;  // blockDim = (64,4)
  if (col >= NCLS) return;
  int row = blockIdx.x * 4 + threadIdx.y;
  int stride = gridDim.x * 4;
  float acc = 0.f;
  for (int r = row; r < N; r += stride) acc += h3[(size_t)r * NCLS + col];
  atomicAdd(&pooled[col], acc);
}

// pooled -> out[0:40], log_softmax(pooled) -> out[40:80]
__global__ __launch_bounds__(64) void k_final(const float* __restrict__ pooled,
                                              float* __restrict__ out) {
  int t = threadIdx.x;
  float v = (t < NCLS) ? pooled[t] : -INFINITY;
  float m = v;
  for (int o = 32; o > 0; o >>= 1) m = fmaxf(m, __shfl_xor(m, o));
  float ex = (t < NCLS) ? expf(v - m) : 0.f;
  float s = ex;
  for (int o = 32; o > 0; o >>= 1) s += __shfl_xor(s, o);
  float lse = m + logf(s);
  if (t < NCLS) {
    out[t] = v;
    out[NCLS + t] = v - lse;
  }
}

// ---------------------------------------------------------------------------
extern "C" void kernel_launch(void* const* d_in, const int* in_sizes, int n_in,
                              void* d_out, int out_size, void* d_ws, size_t ws_size,
                              hipStream_t stream) {
  const float* x   = (const float*)d_in[0];
  const int*   ei  = (const int*)d_in[1];
  const float* W1  = (const float*)d_in[2];
  const float* as1 = (const float*)d_in[3];
  const float* ad1 = (const float*)d_in[4];
  const float* b1  = (const float*)d_in[5];
  const float* W2  = (const float*)d_in[6];
  const float* as2 = (const float*)d_in[7];
  const float* ad2 = (const float*)d_in[8];
  const float* b2  = (const float*)d_in[9];
  const float* W3  = (const float*)d_in[10];
  const float* as3 = (const float*)d_in[11];
  const float* ad3 = (const float*)d_in[12];
  const float* b3  = (const float*)d_in[13];
  float* out = (float*)d_out;

  const int N = NN;
  const int E0 = in_sizes[1] / 2;   // 80000
  const int Etot = E0 + N;          // 90000

  // workspace layout
  const size_t NF = (size_t)N * HC1;  // 15M floats
  float* f = (float*)d_ws;
  float* hfeat  = f;            // [N,1500] GEMM output (reused all layers)
  float* hbuf1  = f + NF;       // layer1 output; later layer3 agg + h3
  float* hbuf2  = f + 2 * NF;   // layer2 combined output
  float* asrc   = f + 3 * NF;
  float* adst   = asrc + (size_t)N * H1;
  float* alphab = adst + (size_t)N * H1;
  float* pooled = alphab + (size_t)Etot * H1;
  int* counts  = (int*)(pooled + 64);
  int* offsets = counts + N;
  int* cursor  = offsets + N + 1;
  int* csr_src = cursor + N;
  uintptr_t pp = (uintptr_t)(csr_src + Etot);
  pp = (pp + 15) & ~(uintptr_t)15;
  unsigned short* abf  = (unsigned short*)pp;            // [N][KPAD] bf16
  unsigned short* btbf = abf + (size_t)N * KPAD;         // [1500][KPAD] bf16 max
  float* aggout = hbuf1;            // [N,120] layer3 aggregation
  float* h3     = hbuf1 + 2000000;  // [N,40]

  hipMemsetAsync(counts, 0, (size_t)N * sizeof(int), stream);
  hipMemsetAsync(pooled, 0, 64 * sizeof(float), stream);

  // CSR build
  k_count<<<(Etot + 255) / 256, 256, 0, stream>>>(ei, counts, E0, Etot);
  k_scan<<<1, 256, 0, stream>>>(counts, offsets, cursor, N, Etot);
  k_scatter<<<(Etot + 255) / 256, 256, 0, stream>>>(ei, cursor, csr_src, E0, Etot);

  // ---- Layer 1: GATConv(x; W1) -> hbuf1, concat, +b1, ELU   (K=128)
  {
    k_cvt<<<((long long)N * F_IN + 255) / 256, 256, 0, stream>>>(x, abf, N, F_IN, F_IN);
    k_cvtT<<<((long long)HC1 * F_IN + 255) / 256, 256, 0, stream>>>(W1, btbf, F_IN, HC1, F_IN);
    dim3 grid((HC1 + BN - 1) / BN, (N + BM - 1) / BM);
    gemm_mfma<<<grid, 256, 0, stream>>>(abf, btbf, hfeat, N, F_IN, HC1);
    k_att<<<N, 64, 0, stream>>>(hfeat, as1, ad1, asrc, adst, H1, HID);
    k_stats<<<(N * H1 + 255) / 256, 256, 0, stream>>>(asrc, adst, csr_src, offsets,
                                                      alphab, N, H1);
    k_agg<<<N, 256, 0, stream>>>(hfeat, alphab, csr_src, offsets, b1, nullptr,
                                 hbuf1, HC1, HID, H1, 0);
  }

  // ---- Layer 2: GATConv(hbuf1; W2), h = elu(hbuf1 + conv2) -> hbuf2  (K=1500)
  {
    k_cvt<<<((long long)N * KPAD + 255) / 256, 256, 0, stream>>>(hbuf1, abf, N, HC1, KPAD);
    k_cvtT<<<((long long)HC1 * KPAD + 255) / 256, 256, 0, stream>>>(W2, btbf, HC1, HC1, KPAD);
    dim3 grid((HC1 + BN - 1) / BN, (N + BM - 1) / BM);
    gemm_mfma<<<grid, 256, 0, stream>>>(abf, btbf, hfeat, N, KPAD, HC1);
    k_att<<<N, 64, 0, stream>>>(hfeat, as2, ad2, asrc, adst, H1, HID);
    k_stats<<<(N * H1 + 255) / 256, 256, 0, stream>>>(asrc, adst, csr_src, offsets,
                                                      alphab, N, H1);
    k_agg<<<N, 256, 0, stream>>>(hfeat, alphab, csr_src, offsets, b2, hbuf1,
                                 hbuf2, HC1, HID, H1, 1);
  }

  // ---- Layer 3: GATConv(hbuf2; W3), mean over heads, +b3 -> h3  (K=1500,N=120)
  {
    k_cvt<<<((long long)N * KPAD + 255) / 256, 256, 0, stream>>>(hbuf2, abf, N, HC1, KPAD);
    k_cvtT<<<((long long)HC3 * KPAD + 255) / 256, 256, 0, stream>>>(W3, btbf, HC1, HC3, KPAD);
    dim3 grid((HC3 + BN - 1) / BN, (N + BM - 1) / BM);
    gemm_mfma<<<grid, 256, 0, stream>>>(abf, btbf, hfeat, N, KPAD, HC3);
    k_att<<<N, 64, 0, stream>>>(hfeat, as3, ad3, asrc, adst, H3, NCLS);
    k_stats<<<(N * H3 + 255) / 256, 256, 0, stream>>>(asrc, adst, csr_src, offsets,
                                                      alphab, N, H3);
    k_agg<<<N, 256, 0, stream>>>(hfeat, alphab, csr_src, offsets, nullptr, nullptr,
                                 aggout, HC3, NCLS, H3, 2);
    k_mean3<<<(N * NCLS + 255) / 256, 256, 0, stream>>>(aggout, b3, h3, N);
  }

  // ---- Pool + log_softmax
  k_pool<<<64, dim3(64, 4), 0, stream>>>(h3, pooled, N);
  k_final<<<1, 64, 0, stream>>>(pooled, out);
}

// Round 3
// 650.226 us; speedup vs baseline: 2.5997x; 1.2821x over previous
//
#include <hip/hip_runtime.h>
#include <hip/hip_bf16.h>
#include <math.h>

// Problem constants (fixed by the reference)
#define NN       10000      // nodes
#define F_IN     128
#define HID      300
#define H1       5
#define H3       3
#define NCLS     40
#define HC1      (H1*HID)   // 1500
#define HC3      (H3*NCLS)  // 120
#define KPAD     1504       // 1500 padded to multiple of 32 (16B-aligned bf16 rows)
#define LD3      128        // layer-3 feature stride (120 padded)
#define NEG_SLOPE 0.2f
#define EPSV     1e-16f

typedef __attribute__((ext_vector_type(8))) short bf16x8;
typedef __attribute__((ext_vector_type(8))) unsigned short u16x8;
typedef __attribute__((ext_vector_type(4))) float f32x4;

__device__ inline unsigned short f2bf(float f) {
  unsigned int u = __builtin_bit_cast(unsigned int, f);
  unsigned int r = (u + 0x7FFFu + ((u >> 16) & 1u)) >> 16;   // RNE
  return (unsigned short)r;
}
__device__ inline float bf2f(unsigned short s) {
  unsigned int u = ((unsigned int)s) << 16;
  return __builtin_bit_cast(float, u);
}

// ---------------------------------------------------------------------------
// CSR build
// ---------------------------------------------------------------------------
__global__ void k_count(const int* __restrict__ ei, int* __restrict__ counts,
                        int E0, int Etot) {
  int e = blockIdx.x * 256 + threadIdx.x;
  if (e >= Etot) return;
  int dst = (e < E0) ? ei[E0 + e] : (e - E0);
  atomicAdd(&counts[dst], 1);
}

__global__ __launch_bounds__(256) void k_scan(const int* __restrict__ counts,
                                              int* __restrict__ offsets,
                                              int* __restrict__ cursor,
                                              int N, int Etot) {
  __shared__ int sh[256];
  const int CH = 40;  // 256*40 = 10240 >= N
  int t = threadIdx.x;
  int base = t * CH;
  int s = 0;
  for (int i = 0; i < CH; i++) {
    int idx = base + i;
    if (idx < N) s += counts[idx];
  }
  sh[t] = s;
  __syncthreads();
  for (int d = 1; d < 256; d <<= 1) {
    int v = (t >= d) ? sh[t - d] : 0;
    __syncthreads();
    sh[t] += v;
    __syncthreads();
  }
  int run = sh[t] - s;  // exclusive prefix
  for (int i = 0; i < CH; i++) {
    int idx = base + i;
    if (idx < N) {
      offsets[idx] = run;
      cursor[idx] = run;
      run += counts[idx];
    }
  }
  if (t == 0) offsets[N] = Etot;
}

__global__ void k_scatter(const int* __restrict__ ei, int* __restrict__ cursor,
                          int* __restrict__ csr_src, int E0, int Etot) {
  int e = blockIdx.x * 256 + threadIdx.x;
  if (e >= Etot) return;
  int src, dst;
  if (e < E0) { src = ei[e]; dst = ei[E0 + e]; }
  else        { src = dst = e - E0; }
  int pos = atomicAdd(&cursor[dst], 1);
  csr_src[pos] = src;
}

// ---------------------------------------------------------------------------
// fp32 -> bf16 casts (layer-1 inputs only)
// ---------------------------------------------------------------------------
__global__ void k_cvt(const float* __restrict__ in, unsigned short* __restrict__ out,
                      int R, int C, int Cpad) {
  long long idx = (long long)blockIdx.x * 256 + threadIdx.x;
  if (idx >= (long long)R * Cpad) return;
  int r = (int)(idx / Cpad), c = (int)(idx - (long long)r * Cpad);
  out[idx] = (c < C) ? f2bf(in[(size_t)r * C + c]) : 0;
}

// in: [K][Nmat] row-major -> out: [Nmat][Kpad] (transposed, zero-padded)
__global__ void k_cvtT(const float* __restrict__ in, unsigned short* __restrict__ out,
                       int K, int Nmat, int Kpad) {
  long long idx = (long long)blockIdx.x * 256 + threadIdx.x;
  if (idx >= (long long)Nmat * Kpad) return;
  int n = (int)(idx / Kpad), k = (int)(idx - (long long)n * Kpad);
  out[idx] = (k < K) ? f2bf(in[(size_t)k * Nmat + n]) : 0;
}

// ---------------------------------------------------------------------------
// MFMA GEMM: Cbf[M,ldc] = A[M,Kpad](bf16) @ Bt[Nmat,Kpad](bf16)^T, bf16 out.
// 128x128 tile, BK=32, 256 thr = 4 waves (2x2), each wave 4x4 of 16x16x32.
// Zero-fills pad columns [Nmat, ldc).
// ---------------------------------------------------------------------------
#define BM 128
#define BN 128
#define BK 32
#define LDST 40   // BK + 8 pad (elements)

__global__ __launch_bounds__(256) void gemm_mfma(
    const unsigned short* __restrict__ A,   // [M][Kpad]
    const unsigned short* __restrict__ Bt,  // [Nmat][Kpad]
    unsigned short* __restrict__ Cbf,       // [M][ldc]
    int M, int Kpad, int Nmat, int ldc) {
  __shared__ unsigned short As[BM * LDST];
  __shared__ unsigned short Bs[BN * LDST];
  int tid = threadIdx.x;
  int lane = tid & 63, wid = tid >> 6;
  int wm = wid >> 1, wn = wid & 1;
  int bm = blockIdx.y * BM, bn = blockIdx.x * BN;
  int quad = lane >> 4, l16 = lane & 15;

  f32x4 acc[4][4] = {};

  for (int kt = 0; kt < Kpad; kt += BK) {
#pragma unroll
    for (int h = 0; h < 2; h++) {
      int i = tid + h * 256;          // chunk id in [0,512)
      int row = i >> 2, seg = i & 3;  // 4x16B chunks per 64B row-slice
      int ar = bm + row; ar = ar < M ? ar : M - 1;
      float4 av = *(const float4*)(A + (size_t)ar * Kpad + kt + seg * 8);
      *(float4*)(As + row * LDST + seg * 8) = av;
      int br = bn + row; br = br < Nmat ? br : Nmat - 1;
      float4 bv = *(const float4*)(Bt + (size_t)br * Kpad + kt + seg * 8);
      *(float4*)(Bs + row * LDST + seg * 8) = bv;
    }
    __syncthreads();
    bf16x8 af[4], bfr[4];
#pragma unroll
    for (int i = 0; i < 4; i++) {
      af[i]  = *(const bf16x8*)(As + (wm * 64 + i * 16 + l16) * LDST + quad * 8);
      bfr[i] = *(const bf16x8*)(Bs + (wn * 64 + i * 16 + l16) * LDST + quad * 8);
    }
#pragma unroll
    for (int i = 0; i < 4; i++)
#pragma unroll
      for (int j = 0; j < 4; j++)
        acc[i][j] = __builtin_amdgcn_mfma_f32_16x16x32_bf16(af[i], bfr[j], acc[i][j], 0, 0, 0);
    __syncthreads();
  }

#pragma unroll
  for (int i = 0; i < 4; i++) {
    int rowb = bm + wm * 64 + i * 16 + quad * 4;
#pragma unroll
    for (int j = 0; j < 4; j++) {
      int col = bn + wn * 64 + j * 16 + l16;
      if (col < ldc) {
        bool live = col < Nmat;
#pragma unroll
        for (int r = 0; r < 4; r++) {
          int row = rowb + r;
          if (row < M) Cbf[(size_t)row * ldc + col] = live ? f2bf(acc[i][j][r]) : 0;
        }
      }
    }
  }
}

// ---------------------------------------------------------------------------
// Attention coefficients from bf16 features
// ---------------------------------------------------------------------------
__global__ __launch_bounds__(64) void k_att(const unsigned short* __restrict__ hfeat,
                                            int ldh,
                                            const float* __restrict__ att_s,
                                            const float* __restrict__ att_d,
                                            float* __restrict__ asrc,
                                            float* __restrict__ adst,
                                            int H, int C) {
  int n = blockIdx.x;
  int t = threadIdx.x;
  const unsigned short* hr = hfeat + (size_t)n * ldh;
  for (int h = 0; h < H; h++) {
    float ps = 0.f, pd = 0.f;
    for (int c = t; c < C; c += 64) {
      float v = bf2f(hr[h * C + c]);
      ps += v * att_s[h * C + c];
      pd += v * att_d[h * C + c];
    }
    for (int o = 32; o > 0; o >>= 1) {
      ps += __shfl_down(ps, o);
      pd += __shfl_down(pd, o);
    }
    if (t == 0) {
      asrc[n * H + h] = ps;
      adst[n * H + h] = pd;
    }
  }
}

// ---------------------------------------------------------------------------
// Per-(node,head) softmax over incoming edges; writes normalized alpha.
// ---------------------------------------------------------------------------
__global__ void k_stats(const float* __restrict__ asrc,
                        const float* __restrict__ adst,
                        const int* __restrict__ csr_src,
                        const int* __restrict__ offsets,
                        float* __restrict__ alpha, int N, int H) {
  int t = blockIdx.x * 256 + threadIdx.x;
  if (t >= N * H) return;
  int n = t / H, h = t - n * H;
  int s0 = offsets[n], s1 = offsets[n + 1];
  float ad = adst[t];
  float m = -1e30f;
  for (int p = s0; p < s1; p++) {
    float v = asrc[csr_src[p] * H + h] + ad;
    v = v > 0.f ? v : NEG_SLOPE * v;
    m = fmaxf(m, v);
  }
  float sum = 0.f;
  for (int p = s0; p < s1; p++) {
    float v = asrc[csr_src[p] * H + h] + ad;
    v = v > 0.f ? v : NEG_SLOPE * v;
    float ex = expf(v - m);
    alpha[p * H + h] = ex;
    sum += ex;
  }
  float r = 1.f / (sum + EPSV);
  for (int p = s0; p < s1; p++) alpha[p * H + h] *= r;
}

// ---------------------------------------------------------------------------
// Aggregation from bf16 features: acc[n,col] = sum_e alpha[e,h(col)] * h[src_e,col]
// One block per node; thread t owns the 8-wide chunk at col0 = 8*t.
// mode 0: +bias, ELU -> out_f32 AND out_bf (next GEMM's A, zero-padded)
// mode 1: +bias +prev, ELU -> out_bf only
// mode 2: raw agg -> LDS -> head-mean + b3 -> h3 [N][NCLS] fp32
// Pad cols [HCv, ldh) map to s_alpha slot h>=H which is zero-filled -> contribute 0.
// ---------------------------------------------------------------------------
__global__ void k_agg(const unsigned short* __restrict__ hfeat, int ldh,
                      const float* __restrict__ alpha,
                      const int* __restrict__ csr_src,
                      const int* __restrict__ offsets,
                      const float* __restrict__ bias,
                      const float* __restrict__ prev,
                      float* __restrict__ out_f32,
                      unsigned short* __restrict__ out_bf,
                      const float* __restrict__ b3,
                      float* __restrict__ h3,
                      int HCv, int C, int H, int mode) {
  int n = blockIdx.x;
  int t = threadIdx.x;
  int nthr = blockDim.x;
  int s0 = offsets[n], s1 = offsets[n + 1];
  int col0 = t * 8;
  bool active = col0 < ldh;

  int hj[8];
  if (active) {
#pragma unroll
    for (int j = 0; j < 8; j++) hj[j] = (col0 + j) / C;  // <= 7 by construction
  }
  float acc[8] = {};

  __shared__ int s_src[64];
  __shared__ float s_alpha[64 * 8];
  __shared__ float s_out[LD3];  // mode-2 reduction buffer

  for (int base = s0; base < s1; base += 64) {
    int chunk = min(64, s1 - base);
    if (t < chunk) s_src[t] = csr_src[base + t];
    for (int i = t; i < chunk * 8; i += nthr) {
      int e = i >> 3, h = i & 7;
      s_alpha[i] = (h < H) ? alpha[(size_t)(base + e) * H + h] : 0.f;
    }
    __syncthreads();
    if (active) {
      for (int e = 0; e < chunk; e++) {
        const unsigned short* hr = hfeat + (size_t)s_src[e] * ldh + col0;
        u16x8 rv = *(const u16x8*)hr;
        const float* al = s_alpha + e * 8;
#pragma unroll
        for (int j = 0; j < 8; j++) acc[j] += al[hj[j]] * bf2f(rv[j]);
      }
    }
    __syncthreads();
  }

  if (mode == 2) {
    if (active) {
#pragma unroll
      for (int j = 0; j < 8; j++) s_out[col0 + j] = acc[j];
    }
    __syncthreads();
    if (t < NCLS)
      h3[(size_t)n * NCLS + t] =
          (s_out[t] + s_out[NCLS + t] + s_out[2 * NCLS + t]) * (1.f / 3.f) + b3[t];
    return;
  }

  if (!active) return;
#pragma unroll
  for (int j = 0; j < 8; j++) {
    int col = col0 + j;
    float v = 0.f;
    if (col < HCv) {
      v = acc[j] + bias[col];
      if (mode == 1) v += prev[(size_t)n * HCv + col];
      v = v > 0.f ? v : (expf(v) - 1.f);  // ELU
      if (out_f32) out_f32[(size_t)n * HCv + col] = v;
    }
    out_bf[(size_t)n * ldh + col] = (col < HCv) ? f2bf(v) : 0;
  }
}

// Pooled column sums
__global__ void k_pool(const float* __restrict__ h3, float* __restrict__ pooled,
                       int N) {
  int col = threadIdx.x;  // blockDim = (64,4)
  if (col >= NCLS) return;
  int row = blockIdx.x * 4 + threadIdx.y;
  int stride = gridDim.x * 4;
  float acc = 0.f;
  for (int r = row; r < N; r += stride) acc += h3[(size_t)r * NCLS + col];
  atomicAdd(&pooled[col], acc);
}

// pooled -> out[0:40], log_softmax(pooled) -> out[40:80]
__global__ __launch_bounds__(64) void k_final(const float* __restrict__ pooled,
                                              float* __restrict__ out) {
  int t = threadIdx.x;
  float v = (t < NCLS) ? pooled[t] : -INFINITY;
  float m = v;
  for (int o = 32; o > 0; o >>= 1) m = fmaxf(m, __shfl_xor(m, o));
  float ex = (t < NCLS) ? expf(v - m) : 0.f;
  float s = ex;
  for (int o = 32; o > 0; o >>= 1) s += __shfl_xor(s, o);
  float lse = m + logf(s);
  if (t < NCLS) {
    out[t] = v;
    out[NCLS + t] = v - lse;
  }
}

// ---------------------------------------------------------------------------
extern "C" void kernel_launch(void* const* d_in, const int* in_sizes, int n_in,
                              void* d_out, int out_size, void* d_ws, size_t ws_size,
                              hipStream_t stream) {
  const float* x   = (const float*)d_in[0];
  const int*   ei  = (const int*)d_in[1];
  const float* W1  = (const float*)d_in[2];
  const float* as1 = (const float*)d_in[3];
  const float* ad1 = (const float*)d_in[4];
  const float* b1  = (const float*)d_in[5];
  const float* W2  = (const float*)d_in[6];
  const float* as2 = (const float*)d_in[7];
  const float* ad2 = (const float*)d_in[8];
  const float* b2  = (const float*)d_in[9];
  const float* W3  = (const float*)d_in[10];
  const float* as3 = (const float*)d_in[11];
  const float* ad3 = (const float*)d_in[12];
  const float* b3  = (const float*)d_in[13];
  float* out = (float*)d_out;

  const int N = NN;
  const int E0 = in_sizes[1] / 2;   // 80000
  const int Etot = E0 + N;          // 90000

  // workspace layout
  float* f = (float*)d_ws;
  float* hbuf1  = f;                               // [N,1500] fp32 (residual)
  float* asrc   = f + (size_t)N * HC1;
  float* adst   = asrc + (size_t)N * H1;
  float* alphab = adst + (size_t)N * H1;           // [Etot,5]
  float* pooled = alphab + (size_t)Etot * H1;      // [64]
  float* h3     = pooled + 64;                     // [N,40]
  int* counts  = (int*)(h3 + (size_t)N * NCLS);
  int* offsets = counts + N;
  int* cursor  = offsets + N + 1;
  int* csr_src = cursor + N;
  uintptr_t pp = (uintptr_t)(csr_src + Etot);
  pp = (pp + 15) & ~(uintptr_t)15;
  unsigned short* hfbf = (unsigned short*)pp;       // [N][KPAD] GEMM output
  unsigned short* abf  = hfbf + (size_t)N * KPAD;   // [N][KPAD] GEMM A input
  unsigned short* btbf = abf + (size_t)N * KPAD;    // [1500][KPAD] W^T

  hipMemsetAsync(counts, 0, (size_t)N * sizeof(int), stream);
  hipMemsetAsync(pooled, 0, 64 * sizeof(float), stream);

  // CSR build
  k_count<<<(Etot + 255) / 256, 256, 0, stream>>>(ei, counts, E0, Etot);
  k_scan<<<1, 256, 0, stream>>>(counts, offsets, cursor, N, Etot);
  k_scatter<<<(Etot + 255) / 256, 256, 0, stream>>>(ei, cursor, csr_src, E0, Etot);

  // ---- Layer 1: GATConv(x; W1) -> hbuf1 (fp32) + abf (bf16), ELU   (K=128)
  {
    k_cvt<<<((long long)N * F_IN + 255) / 256, 256, 0, stream>>>(x, abf, N, F_IN, F_IN);
    k_cvtT<<<((long long)HC1 * F_IN + 255) / 256, 256, 0, stream>>>(W1, btbf, F_IN, HC1, F_IN);
    dim3 grid((HC1 + BN - 1) / BN, (N + BM - 1) / BM);
    gemm_mfma<<<grid, 256, 0, stream>>>(abf, btbf, hfbf, N, F_IN, HC1, KPAD);
    k_att<<<N, 64, 0, stream>>>(hfbf, KPAD, as1, ad1, asrc, adst, H1, HID);
    k_stats<<<(N * H1 + 255) / 256, 256, 0, stream>>>(asrc, adst, csr_src, offsets,
                                                      alphab, N, H1);
    k_agg<<<N, 192, 0, stream>>>(hfbf, KPAD, alphab, csr_src, offsets, b1, nullptr,
                                 hbuf1, abf, nullptr, nullptr, HC1, HID, H1, 0);
  }

  // ---- Layer 2: GATConv(abf; W2), h = elu(hbuf1 + conv2) -> abf (bf16)  (K=1504)
  {
    k_cvtT<<<((long long)HC1 * KPAD + 255) / 256, 256, 0, stream>>>(W2, btbf, HC1, HC1, KPAD);
    dim3 grid((HC1 + BN - 1) / BN, (N + BM - 1) / BM);
    gemm_mfma<<<grid, 256, 0, stream>>>(abf, btbf, hfbf, N, KPAD, HC1, KPAD);
    k_att<<<N, 64, 0, stream>>>(hfbf, KPAD, as2, ad2, asrc, adst, H1, HID);
    k_stats<<<(N * H1 + 255) / 256, 256, 0, stream>>>(asrc, adst, csr_src, offsets,
                                                      alphab, N, H1);
    k_agg<<<N, 192, 0, stream>>>(hfbf, KPAD, alphab, csr_src, offsets, b2, hbuf1,
                                 nullptr, abf, nullptr, nullptr, HC1, HID, H1, 1);
  }

  // ---- Layer 3: GATConv(abf; W3), head-mean + b3 -> h3  (K=1504, Nmat=120)
  {
    k_cvtT<<<((long long)HC3 * KPAD + 255) / 256, 256, 0, stream>>>(W3, btbf, HC1, HC3, KPAD);
    dim3 grid((HC3 + BN - 1) / BN, (N + BM - 1) / BM);
    gemm_mfma<<<grid, 256, 0, stream>>>(abf, btbf, hfbf, N, KPAD, HC3, LD3);
    k_att<<<N, 64, 0, stream>>>(hfbf, LD3, as3, ad3, asrc, adst, H3, NCLS);
    k_stats<<<(N * H3 + 255) / 256, 256, 0, stream>>>(asrc, adst, csr_src, offsets,
                                                      alphab, N, H3);
    k_agg<<<N, 64, 0, stream>>>(hfbf, LD3, alphab, csr_src, offsets, nullptr, nullptr,
                                nullptr, nullptr, b3, h3, HC3, NCLS, H3, 2);
  }

  // ---- Pool + log_softmax
  k_pool<<<64, dim3(64, 4), 0, stream>>>(h3, pooled, N);
  k_final<<<1, 64, 0, stream>>>(pooled, out);
}